// Round 4
// baseline (143.543 us; speedup 1.0000x reference)
//
#include <hip/hip_runtime.h>
#include <stdint.h>

#define BB 8
#define LLEN 16384
#define CC 64
#define TOUT 8186
#define TILE_T 32
#define NROWS 76            // 2*TILE_T + 12 halo rows
#define SXS 68              // fp32 words/row: 272B, 16B-aligned
#define SXGS 72             // shorts/row: 144B, 16B-aligned
#define YNS 65

typedef __attribute__((ext_vector_type(8))) short short8;
typedef __attribute__((ext_vector_type(4))) float float4v;

__device__ inline short f2bf(float f) {
  union { float f; uint32_t u; } v; v.f = f;
  uint32_t r = v.u + 0x7fffu + ((v.u >> 16) & 1u);
  return (short)(r >> 16);
}
__device__ inline float tanh_fast(float a) {
  float e = __expf(2.0f * a);
  return 1.0f - 2.0f / (e + 1.0f);       // saturates exactly at +/-1
}

// Pack fp32 weights (C,C,K) -> bf16 MFMA B-fragments, n = kk*64 + d.
__global__ void prep_frags(const float* __restrict__ weights,
                           unsigned short* __restrict__ wfrag)
{
  int bid = blockIdx.x, tid = threadIdx.x;     // 56 blocks = 28 ntiles x 2 khalves
  int nt = bid >> 1, kh = bid & 1;
  for (int e = tid; e < 512; e += 256) {
    int ln = e >> 3, j = e & 7;
    int kk = nt >> 2;                          // nt = kk*4 + dq
    int d  = (nt & 3) * 16 + (ln & 15);
    int cp = kh * 32 + (ln >> 4) * 8 + j;
    wfrag[(bid * 64 + ln) * 8 + j] = (unsigned short)f2bf(weights[d * 448 + cp * 7 + kk]);
  }
}

__global__ __launch_bounds__(256, 2)
void convblock_main(const float* __restrict__ x,
                    const unsigned short* __restrict__ wfrag,
                    const float* __restrict__ ln_scale,
                    const float* __restrict__ ln_bias,
                    const float* __restrict__ ckm,
                    const float* __restrict__ conv_bias,
                    const float* __restrict__ prelu_slope,
                    float* __restrict__ out)
{
  __shared__ __align__(16) char smem[38208];
  float*          sx2 = (float*)smem;                   // 76*68*4  = 20672
  unsigned short* sxg = (unsigned short*)(smem + 20672);// 64*72*2  = 9216
  float*          ynf = (float*)(smem + 29888);         // 32*65*4  = 8320
  float*          sck = (float*)smem;                   // phase-4 overlay (16384B)

  const int tid  = threadIdx.x;
  const int b    = blockIdx.x >> 8;
  const int t0   = (blockIdx.x & 255) * TILE_T;
  const int lane = tid & 63;
  const int w    = tid >> 6;
  const int l15  = tid & 15;
  const int q    = (tid >> 4) & 3;

  // ---- phase 1: stage x slab rows 2t0 .. 2t0+75 (fp32 + bf16 copies) ----
  {
    const float* xb = x + (size_t)b * ((size_t)LLEN * CC);
    int c = tid & 63, r0 = tid >> 6;
    #pragma unroll
    for (int i = 0; i < 19; ++i) {
      int row = r0 + i * 4;
      int rowg = 2 * t0 + row;
      if (rowg > LLEN - 1) rowg = LLEN - 1;    // only feeds t >= TOUT (never stored)
      float v = xb[(size_t)rowg * CC + c];
      sx2[row * SXS + (c & 15) * 4 + (c >> 4)] = v;
      if (row >= 12) sxg[(row - 12) * SXGS + c] = (unsigned short)f2bf(v);
    }
  }
  __syncthreads();

  // ---- phase 2: gate GEMM D[p][n] = sum_c Xg[p][c]*W[n][c], n = kk*64+d ----
  float4v acc[28];
  #pragma unroll
  for (int i = 0; i < 28; ++i) acc[i] = (float4v){0.f, 0.f, 0.f, 0.f};

  short8 a0 = *(const short8*)&sxg[(16 * w + l15) * SXGS + q * 8];
  short8 a1 = *(const short8*)&sxg[(16 * w + l15) * SXGS + 32 + q * 8];

  #pragma unroll
  for (int nt = 0; nt < 28; ++nt) {
    short8 b0 = *(const short8*)&wfrag[((nt * 2 + 0) * 64 + lane) * 8];
    short8 b1 = *(const short8*)&wfrag[((nt * 2 + 1) * 64 + lane) * 8];
    acc[nt] = __builtin_amdgcn_mfma_f32_16x16x32_bf16(a0, b0, acc[nt], 0, 0, 0);
    acc[nt] = __builtin_amdgcn_mfma_f32_16x16x32_bf16(a1, b1, acc[nt], 0, 0, 0);
  }

  // ---- phase 3: tanh gating + y + LayerNorm (registers) ----
  float y[2][4];
  #pragma unroll
  for (int dlt = 0; dlt < 2; ++dlt)
    #pragma unroll
    for (int dq = 0; dq < 4; ++dq) y[dlt][dq] = 0.f;

  const int dtbase = 8 * w + 2 * q;            // local t = dtbase + dlt
  #pragma unroll
  for (int kk = 0; kk < 7; ++kk) {
    #pragma unroll
    for (int dlt = 0; dlt < 2; ++dlt) {
      int rowe = 2 * (dtbase + dlt) + 2 * kk;
      float4v xe = *(const float4v*)&sx2[rowe * SXS + l15 * 4];
      float4v xo = *(const float4v*)&sx2[(rowe + 1) * SXS + l15 * 4];
      #pragma unroll
      for (int dq = 0; dq < 4; ++dq) {
        float ge = tanh_fast(acc[kk * 4 + dq][2 * dlt + 0]);
        float go = tanh_fast(acc[kk * 4 + dq][2 * dlt + 1]);
        y[dlt][dq] += xe[dq] * ge + xo[dq] * go;
        if (kk == 6) y[dlt][dq] += xe[dq];     // residual x[12+2t] (= kk=6 even row)
      }
    }
  }

  float lnS[4], lnB[4];
  #pragma unroll
  for (int dq = 0; dq < 4; ++dq) {
    lnS[dq] = ln_scale[16 * dq + l15];
    lnB[dq] = ln_bias[16 * dq + l15];
  }

  #pragma unroll
  for (int dlt = 0; dlt < 2; ++dlt) {
    float s1 = y[dlt][0] + y[dlt][1] + y[dlt][2] + y[dlt][3];
    float s2 = y[dlt][0]*y[dlt][0] + y[dlt][1]*y[dlt][1]
             + y[dlt][2]*y[dlt][2] + y[dlt][3]*y[dlt][3];
    #pragma unroll
    for (int m = 1; m < 16; m <<= 1) {         // sum across the 16-lane group
      s1 += __shfl_xor(s1, m, 64);
      s2 += __shfl_xor(s2, m, 64);
    }
    float mu   = s1 * (1.0f / 64.0f);
    float var  = s2 * (1.0f / 64.0f) - mu * mu;
    float rstd = rsqrtf(var + 1e-6f);
    int dt = dtbase + dlt;
    #pragma unroll
    for (int dq = 0; dq < 4; ++dq) {
      int d = 16 * dq + l15;
      ynf[dt * YNS + d] = (y[dlt][dq] - mu) * rstd * lnS[dq] + lnB[dq];
    }
  }
  __syncthreads();                             // ynf ready; sx2 reads done

  // ---- phase 4: stage ck fp32 (overlays sx2), then z + PReLU + add ----
  for (int idx = tid; idx < 4096; idx += 256) sck[idx] = ckm[idx];
  __syncthreads();

  const int t  = tid & 31;
  const int dg = tid >> 5;
  float z[8];
  #pragma unroll
  for (int dd = 0; dd < 8; ++dd) z[dd] = conv_bias[dg * 8 + dd];
  for (int c = 0; c < 64; ++c) {
    float yv = ynf[t * YNS + c];
    float4v wa = *(const float4v*)&sck[c * 64 + dg * 8];
    float4v wb = *(const float4v*)&sck[c * 64 + dg * 8 + 4];
    z[0] += yv * wa[0]; z[1] += yv * wa[1]; z[2] += yv * wa[2]; z[3] += yv * wa[3];
    z[4] += yv * wb[0]; z[5] += yv * wb[1]; z[6] += yv * wb[2]; z[7] += yv * wb[3];
  }

  const float sl = prelu_slope[0];
  const int tg = t0 + t;
  if (tg < TOUT) {
    float4v o0, o1;
    #pragma unroll
    for (int dd = 0; dd < 8; ++dd) {
      float zz = z[dd];
      zz = (zz >= 0.f) ? zz : sl * zz;
      float v = ynf[t * YNS + dg * 8 + dd] + zz;
      if (dd < 4) o0[dd] = v; else o1[dd - 4] = v;
    }
    float* op = out + ((size_t)b * TOUT + tg) * CC + dg * 8;
    *(float4v*)op       = o0;
    *(float4v*)(op + 4) = o1;
  }
}

extern "C" void kernel_launch(void* const* d_in, const int* in_sizes, int n_in,
                              void* d_out, int out_size, void* d_ws, size_t ws_size,
                              hipStream_t stream)
{
  const float* x        = (const float*)d_in[0];
  const float* weights  = (const float*)d_in[1];
  const float* ln_scale = (const float*)d_in[2];
  const float* ln_bias  = (const float*)d_in[3];
  const float* ck       = (const float*)d_in[4];
  const float* cb       = (const float*)d_in[5];
  const float* slope    = (const float*)d_in[6];
  unsigned short* wfrag = (unsigned short*)d_ws;   // 57344 B

  prep_frags<<<56, 256, 0, stream>>>(weights, wfrag);
  convblock_main<<<BB * 256, 256, 0, stream>>>(x, wfrag, ln_scale, ln_bias,
                                               ck, cb, slope, (float*)d_out);
}

// Round 5
// 136.171 us; speedup vs baseline: 1.0541x; 1.0541x over previous
//
#include <hip/hip_runtime.h>
#include <stdint.h>

#define BB 8
#define LLEN 16384
#define CC 64
#define TOUT 8186
#define TILE_T 32
#define NROWS 76            // 2*TILE_T + 12 halo rows
#define SXS 68              // fp32 words/row: 272B, 16B-aligned
#define SXGS 72             // shorts/row: 144B, 16B-aligned
#define YNS 65

typedef __attribute__((ext_vector_type(8))) short short8;
typedef __attribute__((ext_vector_type(4))) float float4v;

__device__ inline short f2bf(float f) {
  union { float f; uint32_t u; } v; v.f = f;
  uint32_t r = v.u + 0x7fffu + ((v.u >> 16) & 1u);
  return (short)(r >> 16);
}
__device__ inline float tanh_fast(float a) {
  float e = __expf(2.0f * a);
  return 1.0f - 2.0f / (e + 1.0f);       // saturates exactly at +/-1
}

// Pack fp32 weights (C,C,K) -> bf16 MFMA B-fragments, n = kk*64 + d.
__global__ void prep_frags(const float* __restrict__ weights,
                           unsigned short* __restrict__ wfrag)
{
  int bid = blockIdx.x, tid = threadIdx.x;     // 56 blocks = 28 ntiles x 2 khalves
  int nt = bid >> 1, kh = bid & 1;
  for (int e = tid; e < 512; e += 256) {
    int ln = e >> 3, j = e & 7;
    int kk = nt >> 2;                          // nt = kk*4 + dq
    int d  = (nt & 3) * 16 + (ln & 15);
    int cp = kh * 32 + (ln >> 4) * 8 + j;
    wfrag[(bid * 64 + ln) * 8 + j] = (unsigned short)f2bf(weights[d * 448 + cp * 7 + kk]);
  }
}

__global__ __launch_bounds__(256, 4)
void convblock_main(const float* __restrict__ x,
                    const unsigned short* __restrict__ wfrag,
                    const float* __restrict__ ln_scale,
                    const float* __restrict__ ln_bias,
                    const float* __restrict__ ckm,
                    const float* __restrict__ conv_bias,
                    const float* __restrict__ prelu_slope,
                    float* __restrict__ out)
{
  __shared__ __align__(16) char smem[29888];
  float*          sx2 = (float*)smem;                    // 76*68*4 = 20672
  unsigned short* sxg = (unsigned short*)(smem + 20672); // 64*72*2 = 9216
  float*          ynf = (float*)(smem + 20672);          // overlays sxg (8320 B)
  float*          sck = (float*)smem;                    // phase-4 overlay (16384 B)

  const int tid  = threadIdx.x;
  const int b    = blockIdx.x >> 8;
  const int t0   = (blockIdx.x & 255) * TILE_T;
  const int lane = tid & 63;
  const int w    = tid >> 6;
  const int l15  = tid & 15;
  const int q    = (tid >> 4) & 3;

  // ---- phase 1: stage x slab rows 2t0 .. 2t0+75 (fp32 swizzled + bf16) ----
  {
    const float* xb = x + (size_t)b * ((size_t)LLEN * CC);
    int c = tid & 63, r0 = tid >> 6;
    #pragma unroll
    for (int i = 0; i < 19; ++i) {
      int row = r0 + i * 4;
      int rowg = 2 * t0 + row;
      if (rowg > LLEN - 1) rowg = LLEN - 1;    // only feeds t >= TOUT (never stored)
      float v = xb[(size_t)rowg * CC + c];
      sx2[row * SXS + (c & 15) * 4 + (c >> 4)] = v;
      if (row >= 12) sxg[(row - 12) * SXGS + c] = (unsigned short)f2bf(v);
    }
  }
  // LN params early (latency overlap with barrier)
  float lnS[4], lnB[4];
  #pragma unroll
  for (int dq = 0; dq < 4; ++dq) {
    lnS[dq] = ln_scale[16 * dq + l15];
    lnB[dq] = ln_bias[16 * dq + l15];
  }
  __syncthreads();

  // A-fragments; after the next barrier sxg is dead (ynf overlays it)
  short8 a0 = *(const short8*)&sxg[(16 * w + l15) * SXGS + q * 8];
  short8 a1 = *(const short8*)&sxg[(16 * w + l15) * SXGS + 32 + q * 8];
  __syncthreads();

  // ---- phase 2+3 fused: per-kk MFMA -> tanh -> y  (keeps 16 AGPRs live) ----
  float y[2][4];
  #pragma unroll
  for (int dlt = 0; dlt < 2; ++dlt)
    #pragma unroll
    for (int dq = 0; dq < 4; ++dq) y[dlt][dq] = 0.f;

  const int dtbase = 8 * w + 2 * q;            // local t = dtbase + dlt
  #pragma unroll
  for (int kk = 0; kk < 7; ++kk) {
    float4v acc[4];
    #pragma unroll
    for (int dq = 0; dq < 4; ++dq) {
      int nt = kk * 4 + dq;
      short8 b0 = *(const short8*)&wfrag[((nt * 2 + 0) * 64 + lane) * 8];
      short8 b1 = *(const short8*)&wfrag[((nt * 2 + 1) * 64 + lane) * 8];
      float4v a = (float4v){0.f, 0.f, 0.f, 0.f};
      a = __builtin_amdgcn_mfma_f32_16x16x32_bf16(a0, b0, a, 0, 0, 0);
      a = __builtin_amdgcn_mfma_f32_16x16x32_bf16(a1, b1, a, 0, 0, 0);
      acc[dq] = a;
    }
    #pragma unroll
    for (int dlt = 0; dlt < 2; ++dlt) {
      int rowe = 2 * (dtbase + dlt) + 2 * kk;
      float4v xe = *(const float4v*)&sx2[rowe * SXS + l15 * 4];
      float4v xo = *(const float4v*)&sx2[(rowe + 1) * SXS + l15 * 4];
      #pragma unroll
      for (int dq = 0; dq < 4; ++dq) {
        float ge = tanh_fast(acc[dq][2 * dlt + 0]);
        float go = tanh_fast(acc[dq][2 * dlt + 1]);
        y[dlt][dq] += xe[dq] * ge + xo[dq] * go;
        if (kk == 6) y[dlt][dq] += xe[dq];     // residual x[12+2t] (= kk=6 even row)
      }
    }
  }

  // ---- LayerNorm (registers + 16-lane shuffle), write ynf (sxg overlay) ----
  #pragma unroll
  for (int dlt = 0; dlt < 2; ++dlt) {
    float s1 = y[dlt][0] + y[dlt][1] + y[dlt][2] + y[dlt][3];
    float s2 = y[dlt][0]*y[dlt][0] + y[dlt][1]*y[dlt][1]
             + y[dlt][2]*y[dlt][2] + y[dlt][3]*y[dlt][3];
    #pragma unroll
    for (int m = 1; m < 16; m <<= 1) {
      s1 += __shfl_xor(s1, m, 64);
      s2 += __shfl_xor(s2, m, 64);
    }
    float mu   = s1 * (1.0f / 64.0f);
    float var  = s2 * (1.0f / 64.0f) - mu * mu;
    float rstd = rsqrtf(var + 1e-6f);
    int dt = dtbase + dlt;
    #pragma unroll
    for (int dq = 0; dq < 4; ++dq) {
      int d = 16 * dq + l15;
      ynf[dt * YNS + d] = (y[dlt][dq] - mu) * rstd * lnS[dq] + lnB[dq];
    }
  }
  __syncthreads();                             // ynf ready; sx2 reads done

  // ---- phase 4: stage ck fp32 (overlays sx2), z = yn@ck + cb, PReLU, add ----
  for (int idx = tid; idx < 4096; idx += 256) sck[idx] = ckm[idx];
  __syncthreads();

  const int t  = tid & 31;
  const int dg = tid >> 5;
  float z[8];
  #pragma unroll
  for (int dd = 0; dd < 8; ++dd) z[dd] = conv_bias[dg * 8 + dd];
  for (int c = 0; c < 64; ++c) {
    float yv = ynf[t * YNS + c];
    float4v wa = *(const float4v*)&sck[c * 64 + dg * 8];
    float4v wb = *(const float4v*)&sck[c * 64 + dg * 8 + 4];
    z[0] += yv * wa[0]; z[1] += yv * wa[1]; z[2] += yv * wa[2]; z[3] += yv * wa[3];
    z[4] += yv * wb[0]; z[5] += yv * wb[1]; z[6] += yv * wb[2]; z[7] += yv * wb[3];
  }

  const float sl = prelu_slope[0];
  const int tg = t0 + t;
  if (tg < TOUT) {
    float4v o0, o1;
    #pragma unroll
    for (int dd = 0; dd < 8; ++dd) {
      float zz = z[dd];
      zz = (zz >= 0.f) ? zz : sl * zz;
      float v = ynf[t * YNS + dg * 8 + dd] + zz;
      if (dd < 4) o0[dd] = v; else o1[dd - 4] = v;
    }
    float* op = out + ((size_t)b * TOUT + tg) * CC + dg * 8;
    *(float4v*)op       = o0;
    *(float4v*)(op + 4) = o1;
  }
}

extern "C" void kernel_launch(void* const* d_in, const int* in_sizes, int n_in,
                              void* d_out, int out_size, void* d_ws, size_t ws_size,
                              hipStream_t stream)
{
  const float* x        = (const float*)d_in[0];
  const float* weights  = (const float*)d_in[1];
  const float* ln_scale = (const float*)d_in[2];
  const float* ln_bias  = (const float*)d_in[3];
  const float* ck       = (const float*)d_in[4];
  const float* cb       = (const float*)d_in[5];
  const float* slope    = (const float*)d_in[6];
  unsigned short* wfrag = (unsigned short*)d_ws;   // 57344 B

  prep_frags<<<56, 256, 0, stream>>>(weights, wfrag);
  convblock_main<<<BB * 256, 256, 0, stream>>>(x, wfrag, ln_scale, ln_bias,
                                               ck, cb, slope, (float*)d_out);
}

// Round 6
// 112.815 us; speedup vs baseline: 1.2724x; 1.2070x over previous
//
#include <hip/hip_runtime.h>
#include <stdint.h>

#define BB 8
#define LLEN 16384
#define CC 64
#define TOUT 8186
#define TILE_T 32
#define NROWS 76            // 2*TILE_T + 12 halo rows
#define SXS 68              // fp32 words/row (272B)
#define SXGS 72             // shorts/row (144B)
#define YNS 66              // fp32 words/row (2-way-free banking)
#define YNBS 72             // shorts/row

typedef __attribute__((ext_vector_type(8))) short short8;
typedef __attribute__((ext_vector_type(4))) float float4v;
typedef __attribute__((ext_vector_type(4))) unsigned short ushort4v;

__device__ inline unsigned short f2bf(float f) {
  union { float f; uint32_t u; } v; v.f = f;
  uint32_t r = v.u + 0x7fffu + ((v.u >> 16) & 1u);
  return (unsigned short)(r >> 16);
}
__device__ inline float rcp_fast(float x) {
  float r;
  asm("v_rcp_f32 %0, %1" : "=v"(r) : "v"(x));
  return r;
}
__device__ inline float tanh_fast(float a) {
  float e = __expf(2.0f * a);                  // native v_exp_f32 path
  return 1.0f - 2.0f * rcp_fast(e + 1.0f);     // saturates at +/-1
}

// Pack fp32 weights (C,C,K) -> bf16 MFMA B-frags (n = kk*64+d), and
// fp32 conv_kernel (C,C) -> bf16 B-frags (n = o, k = c).
__global__ void prep_frags(const float* __restrict__ weights,
                           const float* __restrict__ ck,
                           unsigned short* __restrict__ wfrag,
                           unsigned short* __restrict__ ckfrag)
{
  int bid = blockIdx.x, tid = threadIdx.x;
  if (bid < 56) {                       // 28 ntiles x 2 khalves
    int nt = bid >> 1, kh = bid & 1;
    for (int e = tid; e < 512; e += 256) {
      int ln = e >> 3, j = e & 7;
      int kk = nt >> 2;                 // nt = kk*4 + dq
      int d  = (nt & 3) * 16 + (ln & 15);
      int cp = kh * 32 + (ln >> 4) * 8 + j;
      wfrag[(bid * 64 + ln) * 8 + j] = f2bf(weights[d * 448 + cp * 7 + kk]);
    }
  } else {                              // conv kernel: 4 ntiles x 2 khalves
    int bb2 = bid - 56;
    int nt = bb2 >> 1, kh = bb2 & 1;
    for (int e = tid; e < 512; e += 256) {
      int ln = e >> 3, j = e & 7;
      int oo = nt * 16 + (ln & 15);
      int c2 = kh * 32 + (ln >> 4) * 8 + j;
      ckfrag[(bb2 * 64 + ln) * 8 + j] = f2bf(ck[c2 * 64 + oo]);
    }
  }
}

__global__ __launch_bounds__(256, 4)
void convblock_main(const float* __restrict__ x,
                    const unsigned short* __restrict__ wfrag,
                    const unsigned short* __restrict__ ckfrag,
                    const float* __restrict__ ln_scale,
                    const float* __restrict__ ln_bias,
                    const float* __restrict__ conv_bias,
                    const float* __restrict__ prelu_slope,
                    float* __restrict__ out)
{
  __shared__ __align__(16) char smem[29888];
  float*          sx2 = (float*)smem;                    // [0, 20672)
  unsigned short* ynb = (unsigned short*)smem;           // overlay after B3 (4608 B)
  unsigned short* sxg = (unsigned short*)(smem + 20672); // 9216 B
  float*          ynf = (float*)(smem + 20672);          // overlay after B2 (8448 B)

  const int tid  = threadIdx.x;
  const int b    = blockIdx.x >> 8;
  const int t0   = (blockIdx.x & 255) * TILE_T;
  const int lane = tid & 63;
  const int w    = tid >> 6;
  const int l15  = tid & 15;
  const int q    = (tid >> 4) & 3;

  // ---- phase 1: stage x slab rows 2t0..2t0+75, float4 loads ----
  {
    const float* xb = x + (size_t)b * ((size_t)LLEN * CC);
    #pragma unroll
    for (int i = 0; i < 5; ++i) {
      int idx = tid + i * 256;                  // [0, 1216) float4s
      if (idx < NROWS * 16) {
        int row = idx >> 4, f4 = idx & 15, c0 = f4 * 4;
        int rowg = 2 * t0 + row;
        if (rowg > LLEN - 1) rowg = LLEN - 1;   // only feeds t >= TOUT (never stored)
        float4v v = *(const float4v*)(xb + (size_t)rowg * CC + c0);
        int base = row * SXS + 16 * (f4 & 3) + (f4 >> 2);  // swizzle (c&15)*4+(c>>4)
        sx2[base + 0]  = v[0];
        sx2[base + 4]  = v[1];
        sx2[base + 8]  = v[2];
        sx2[base + 12] = v[3];
        if (row >= 12) {
          ushort4v p;
          p[0] = f2bf(v[0]); p[1] = f2bf(v[1]); p[2] = f2bf(v[2]); p[3] = f2bf(v[3]);
          *(ushort4v*)&sxg[(row - 12) * SXGS + c0] = p;
        }
      }
    }
  }
  float lnS[4], lnB[4];
  #pragma unroll
  for (int dq = 0; dq < 4; ++dq) {
    lnS[dq] = ln_scale[16 * dq + l15];
    lnB[dq] = ln_bias[16 * dq + l15];
  }
  __syncthreads();                              // B1

  short8 a0 = *(const short8*)&sxg[(16 * w + l15) * SXGS + q * 8];
  short8 a1 = *(const short8*)&sxg[(16 * w + l15) * SXGS + 32 + q * 8];
  __syncthreads();                              // B2: sxg dead, ynf may overlay

  // ---- phase 2+3 fused: per-kk MFMA -> tanh -> y ----
  float y[2][4];
  #pragma unroll
  for (int dlt = 0; dlt < 2; ++dlt)
    #pragma unroll
    for (int dq = 0; dq < 4; ++dq) y[dlt][dq] = 0.f;

  const int dtbase = 8 * w + 2 * q;             // local t = dtbase + dlt
  #pragma unroll
  for (int kk = 0; kk < 7; ++kk) {
    float4v acc[4];
    #pragma unroll
    for (int dq = 0; dq < 4; ++dq) {
      int nt = kk * 4 + dq;
      short8 b0 = *(const short8*)&wfrag[((nt * 2 + 0) * 64 + lane) * 8];
      short8 b1 = *(const short8*)&wfrag[((nt * 2 + 1) * 64 + lane) * 8];
      float4v a = (float4v){0.f, 0.f, 0.f, 0.f};
      a = __builtin_amdgcn_mfma_f32_16x16x32_bf16(a0, b0, a, 0, 0, 0);
      a = __builtin_amdgcn_mfma_f32_16x16x32_bf16(a1, b1, a, 0, 0, 0);
      acc[dq] = a;
    }
    #pragma unroll
    for (int dlt = 0; dlt < 2; ++dlt) {
      int rowe = 2 * (dtbase + dlt) + 2 * kk;
      float4v xe = *(const float4v*)&sx2[rowe * SXS + l15 * 4];
      float4v xo = *(const float4v*)&sx2[(rowe + 1) * SXS + l15 * 4];
      #pragma unroll
      for (int dq = 0; dq < 4; ++dq) {
        float ge = tanh_fast(acc[dq][2 * dlt + 0]);
        float go = tanh_fast(acc[dq][2 * dlt + 1]);
        y[dlt][dq] += xe[dq] * ge + xo[dq] * go;
        if (kk == 6) y[dlt][dq] += xe[dq];      // residual x[12+2t] (= kk=6 even row)
      }
    }
  }

  // ---- LayerNorm (registers + 16-lane shuffle) ----
  float ynr[2][4];
  #pragma unroll
  for (int dlt = 0; dlt < 2; ++dlt) {
    float s1 = y[dlt][0] + y[dlt][1] + y[dlt][2] + y[dlt][3];
    float s2 = y[dlt][0]*y[dlt][0] + y[dlt][1]*y[dlt][1]
             + y[dlt][2]*y[dlt][2] + y[dlt][3]*y[dlt][3];
    #pragma unroll
    for (int m = 1; m < 16; m <<= 1) {
      s1 += __shfl_xor(s1, m, 64);
      s2 += __shfl_xor(s2, m, 64);
    }
    float mu   = s1 * (1.0f / 64.0f);
    float var  = s2 * (1.0f / 64.0f) - mu * mu;
    float rstd = rsqrtf(var + 1e-6f);
    int dt = dtbase + dlt;
    #pragma unroll
    for (int dq = 0; dq < 4; ++dq) {
      float yn = (y[dlt][dq] - mu) * rstd * lnS[dq] + lnB[dq];
      ynr[dlt][dq] = yn;
      ynf[dt * YNS + 16 * dq + l15] = yn;       // sxg-overlay region
    }
  }
  __syncthreads();                              // B3: sx2 reads done

  // ---- write ynb bf16 A-frags (sx2 overlay) ----
  #pragma unroll
  for (int dlt = 0; dlt < 2; ++dlt)
    #pragma unroll
    for (int dq = 0; dq < 4; ++dq)
      ynb[(dtbase + dlt) * YNBS + 16 * dq + l15] = f2bf(ynr[dlt][dq]);
  __syncthreads();                              // B4

  // ---- phase 4: z = yn@ck + cb via MFMA, PReLU, out = yn + z ----
  const float sl = prelu_slope[0];
  const int   o  = 16 * w + l15;                // wave w owns o-tile w
  const float cb = conv_bias[o];
  short8 bf0 = *(const short8*)&ckfrag[((w * 2 + 0) * 64 + lane) * 8];
  short8 bf1 = *(const short8*)&ckfrag[((w * 2 + 1) * 64 + lane) * 8];
  #pragma unroll
  for (int mt = 0; mt < 2; ++mt) {
    short8 af0 = *(const short8*)&ynb[(mt * 16 + l15) * YNBS + q * 8];
    short8 af1 = *(const short8*)&ynb[(mt * 16 + l15) * YNBS + 32 + q * 8];
    float4v zc = (float4v){0.f, 0.f, 0.f, 0.f};
    zc = __builtin_amdgcn_mfma_f32_16x16x32_bf16(af0, bf0, zc, 0, 0, 0);
    zc = __builtin_amdgcn_mfma_f32_16x16x32_bf16(af1, bf1, zc, 0, 0, 0);
    #pragma unroll
    for (int r = 0; r < 4; ++r) {
      int t  = mt * 16 + 4 * q + r;
      int tg = t0 + t;
      if (tg < TOUT) {
        float z = zc[r] + cb;
        z = (z >= 0.f) ? z : sl * z;
        out[((size_t)b * TOUT + tg) * CC + o] = ynf[t * YNS + o] + z;
      }
    }
  }
}

extern "C" void kernel_launch(void* const* d_in, const int* in_sizes, int n_in,
                              void* d_out, int out_size, void* d_ws, size_t ws_size,
                              hipStream_t stream)
{
  const float* x        = (const float*)d_in[0];
  const float* weights  = (const float*)d_in[1];
  const float* ln_scale = (const float*)d_in[2];
  const float* ln_bias  = (const float*)d_in[3];
  const float* ck       = (const float*)d_in[4];
  const float* cb       = (const float*)d_in[5];
  const float* slope    = (const float*)d_in[6];
  unsigned short* wfrag  = (unsigned short*)d_ws;                  // 57344 B
  unsigned short* ckfrag = (unsigned short*)((char*)d_ws + 57344); // 8192 B

  prep_frags<<<64, 256, 0, stream>>>(weights, ck, wfrag, ckfrag);
  convblock_main<<<BB * 256, 256, 0, stream>>>(x, wfrag, ckfrag, ln_scale,
                                               ln_bias, cb, slope, (float*)d_out);
}